// Round 12
// baseline (295.989 us; speedup 1.0000x reference)
//
#include <hip/hip_runtime.h>

constexpr int W    = 96;
constexpr int NPIX = 9216;
constexpr int NPK  = 18;          // 72 channels = 18 float4 packs (DC, cos1..35, sin1..35, pad)
constexpr int NM   = 35;
constexpr int TB   = 384;
constexpr int RPS  = 24;          // rows per stripe
constexpr int PPS  = RPS*W;       // 2304 px per stripe

constexpr float LCLIP = 18.420681f;   // -log(1e-8)

// ---- init: Fourier basis tables, pixel-major packs (libm-accurate, as in R10) ----
__global__ __launch_bounds__(256) void k_init(const float* __restrict__ img,
                                              float4* __restrict__ Bsplat,
                                              float4* __restrict__ Bslice){
    int px = blockIdx.x*256 + threadIdx.x;
    if (px >= NPIX) return;
    float th = img[px] * 0.0122718463f;            // 2*pi/512
    float sp[72], sl[72];
    sp[0] = 0.6923648f;  sl[0] = 1.f;              // DC: 10*sqrt(400*pi)/512 (compat 10 folded)
    #pragma unroll
    for (int m = 1; m <= NM; ++m){
        float s, c;
        sincosf((float)m*th, &s, &c);              // libm: accurate reduction
        float A = 1.3847296f * __expf(-0.0150598f*(float)(m*m));
        sp[m]    = A*c;  sl[m]    = c;             // cos channels 1..35
        sp[NM+m] = A*s;  sl[NM+m] = s;             // sin channels 36..70
    }
    sp[71] = 0.f; sl[71] = 0.f;                    // pad channel
    float4* dsp = Bsplat + (size_t)px*NPK;
    float4* dsl = Bslice + (size_t)px*NPK;
    #pragma unroll
    for (int pk = 0; pk < NPK; ++pk){
        dsp[pk] = make_float4(sp[4*pk], sp[4*pk+1], sp[4*pk+2], sp[4*pk+3]);
        dsl[pk] = make_float4(sl[4*pk], sl[4*pk+1], sl[4*pk+2], sl[4*pk+3]);
    }
}

// ---- one launch = one mean-field iteration; block = one output column X ----
// MODE 0: q0 from mask; grid 192 (blocks 96..191 run the ones-pipeline -> ksum).
// MODE 1: reconstruct q_t from msgprev; write msg_t.
// MODE 2: reconstruct q4; compute msg4 and the final argmax directly.
template<int MODE>
__global__ __launch_bounds__(TB) void k_it(
        const int* __restrict__ mask,
        const float4* __restrict__ Bsplat, const float4* __restrict__ Bslice,
        const float* __restrict__ msgprev, float* __restrict__ msgcur,
        float* __restrict__ ksum,
        const float* __restrict__ qprev, float* __restrict__ qcur,
        float* __restrict__ out)
{
    __shared__ float4 UN[96*19];     // phase A/C: qs rows (padded 97); phase D/E: V4
    __shared__ float4 H4[96*19];     // H-conv result [y][pk]
    __shared__ float  w50[96], w3t[96], t50v[192], t3v[192], H3[96], V3[96], qcol[96];

    const int  t    = threadIdx.x;
    const bool ONES = (MODE==0) && (blockIdx.x >= 96);
    const int  X    = blockIdx.x % 96;
    float* qs = (float*)UN;          // [RPS][97] padded rows

    if (t < 96){
        float d = (float)(X - t);
        w50[t] = __expf(-d*d*(1.f/5000.f));        // bilateral spatial taps vs own col
        w3t[t] = __expf(-d*d*(1.f/18.f));          // sxy=3 gaussian taps vs own col
    } else if (t < 288){
        int i = t - 96;                            // 0..191: d = i-96
        float d = (float)(i - 96);
        t50v[i] = __expf(-d*d*(1.f/5000.f));
        t3v[i]  = __expf(-d*d*(1.f/18.f));
    }

    // ---- stripes: A (recon q rows) + C (H-conv rows) ----
    for (int s = 0; s < 4; ++s){
        __syncthreads();                           // tables ready / qs reusable
        #pragma unroll
        for (int k = 0; k < PPS/TB; ++k){          // 6 px per thread
            int l  = t + k*TB;
            int px = s*PPS + l;
            float q;
            if (ONES){
                q = 1.f;
            } else if (MODE == 0){
                float duv = (mask[px]==0) ? LCLIP : -LCLIP;
                q = 1.f/(1.f+__expf(duv));
            } else {
                float duv = (mask[px]==0) ? LCLIP : -LCLIP;
                float delta = duv + ksum[px] - 2.f*(msgprev[px] - 13.f*qprev[px]);
                q = 1.f/(1.f+__expf(delta));
            }
            int yl = l/96, xx = l - yl*96;
            qs[yl*97 + xx] = q;
            if (!ONES){
                if (blockIdx.x == 0) qcur[px] = q;   // designated writer (next iter's diag)
                if (xx == X) qcol[s*RPS + yl] = q;   // own column's q (final diag)
            }
        }
        __syncthreads();
        // H-conv for this stripe: tasks (row, pk) ; pk==18 -> sxy=3 channel
        for (int tau = t; tau < RPS*19; tau += TB){
            int yl = tau/19, pk = tau - yl*19;
            int y  = s*RPS + yl;
            const float* qrow = qs + yl*97;
            if (pk < 18){
                const float4* brow = Bsplat + ((size_t)y*96)*NPK + pk;
                float4 a = make_float4(0.f,0.f,0.f,0.f);
                #pragma unroll 8
                for (int xp = 0; xp < 96; ++xp){
                    float  qw = qrow[xp]*w50[xp];
                    float4 b  = brow[(size_t)xp*NPK];
                    a.x = fmaf(qw,b.x,a.x); a.y = fmaf(qw,b.y,a.y);
                    a.z = fmaf(qw,b.z,a.z); a.w = fmaf(qw,b.w,a.w);
                }
                H4[y*19+pk] = a;
            } else {
                float h = 0.f;
                #pragma unroll 8
                for (int xp = 0; xp < 96; ++xp) h = fmaf(qrow[xp], w3t[xp], h);
                H3[y] = h;
            }
        }
    }
    __syncthreads();       // H4/H3 complete; qs dead -> UN becomes V4

    // ---- phase D: V-conv (6-row register tiles), threads 288+ do the sxy=3 channel ----
    if (t < 288){
        int h = t/18, pk = t - h*18;
        int y0 = 6*h;
        float4 a[6];
        #pragma unroll
        for (int i = 0; i < 6; ++i) a[i] = make_float4(0.f,0.f,0.f,0.f);
        for (int yp = 0; yp < 96; ++yp){
            float4 v = H4[yp*19+pk];
            #pragma unroll
            for (int i = 0; i < 6; ++i){
                float wv = t50v[y0+i-yp+96];
                a[i].x = fmaf(wv,v.x,a[i].x); a[i].y = fmaf(wv,v.y,a[i].y);
                a[i].z = fmaf(wv,v.z,a[i].z); a[i].w = fmaf(wv,v.w,a[i].w);
            }
        }
        #pragma unroll
        for (int i = 0; i < 6; ++i) UN[(y0+i)*19+pk] = a[i];
    } else if (t < 384){
        int y = t - 288;
        float v = 0.f;
        for (int yp = 0; yp < 96; ++yp) v = fmaf(H3[yp], t3v[y-yp+96], v);
        V3[y] = v;
    }
    __syncthreads();

    // ---- phase E: slice (f64 dot) + store / final ----
    if (t < 96){
        int y = t, px = y*96 + X;
        const float4* bs = Bslice + (size_t)px*NPK;
        double acc = 0.0;
        #pragma unroll
        for (int pk = 0; pk < 18; ++pk){
            float4 v = UN[y*19+pk];
            float4 b = bs[pk];
            acc += (double)v.x*b.x + (double)v.y*b.y + (double)v.z*b.z + (double)v.w*b.w;
        }
        float msgv = (float)acc + 3.f*V3[y];       // bilateral (compat 10 folded) + gaussian
        if (ONES){
            ksum[px] = msgv - 13.f;                // column sum of K, diagonal removed
        } else if (MODE == 2){
            float duv = (mask[px]==0) ? LCLIP : -LCLIP;
            float delta = duv + ksum[px] - 2.f*(msgv - 13.f*qcol[y]);
            out[px] = (delta > 0.f) ? 1.f : 0.f;   // argmax; tie -> label 0
        } else {
            msgcur[px] = msgv;
        }
    }
}

extern "C" void kernel_launch(void* const* d_in, const int* in_sizes, int n_in,
                              void* d_out, int out_size, void* d_ws, size_t ws_size,
                              hipStream_t stream){
    const float* img  = (const float*)d_in[0];
    const int*   mask = (const int*)d_in[1];
    float* out = (float*)d_out;
    float* ws  = (float*)d_ws;

    constexpr size_t TBL = (size_t)NPIX*NPK*4;     // floats per basis table
    float4* Bsp  = (float4*)ws;
    float4* Bsl  = (float4*)(ws + TBL);
    float*  base = ws + 2*TBL;
    float* msgA = base;
    float* msgB = base + NPIX;
    float* qA   = base + 2*NPIX;
    float* qB   = base + 3*NPIX;
    float* ksum = base + 4*NPIX;

    k_init<<<dim3(36), dim3(256), 0, stream>>>(img, Bsp, Bsl);
    // iter 0: msg0 = K q0 (blocks 0-95) and ksum = K 1 (blocks 96-191)
    k_it<0><<<dim3(192), dim3(TB), 0, stream>>>(mask, Bsp, Bsl, msgB, msgA, ksum, qB, qA, out);
    // iters 1..3
    k_it<1><<<dim3(96), dim3(TB), 0, stream>>>(mask, Bsp, Bsl, msgA, msgB, ksum, qA, qB, out);
    k_it<1><<<dim3(96), dim3(TB), 0, stream>>>(mask, Bsp, Bsl, msgB, msgA, ksum, qB, qA, out);
    k_it<1><<<dim3(96), dim3(TB), 0, stream>>>(mask, Bsp, Bsl, msgA, msgB, ksum, qA, qB, out);
    // iter 4 + final update (iteration 5) + argmax, fused
    k_it<2><<<dim3(96), dim3(TB), 0, stream>>>(mask, Bsp, Bsl, msgB, msgA, ksum, qB, qA, out);
}

// Round 13
// 88.920 us; speedup vs baseline: 3.3287x; 3.3287x over previous
//
#include <hip/hip_runtime.h>

constexpr int W    = 96;
constexpr int NPIX = 9216;
constexpr int NM   = 35;     // Fourier modes (truncation err ~3e-9 per kernel value)
constexpr int NPKB = 18;     // bilateral packs = 72 channels / 4 (DC, cos1..35, sin1..35, pad)
constexpr int NP   = 19;     // + the sxy=3 gaussian "pack"

constexpr float LCLIP = 18.420681f;   // -log(1e-8)

// ---- init: raw Fourier basis table, pack-major float4 per pixel ----
__global__ __launch_bounds__(256) void k_init(const float* __restrict__ img,
                                              float4* __restrict__ B4){
    int px = blockIdx.x*256 + threadIdx.x;
    float th = img[px] * 0.0122718463f;        // 2*pi/512
    float c[72];
    c[0] = 1.f; c[71] = 0.f;
    #pragma unroll
    for (int m = 1; m <= NM; ++m){
        float s, co;
        sincosf((float)m*th, &s, &co);         // libm: accurate reduction
        c[m]    = co;                          // cos channels 1..35
        c[NM+m] = s;                           // sin channels 36..70
    }
    #pragma unroll
    for (int p = 0; p < NPKB; ++p)
        B4[(size_t)p*NPIX + px] = make_float4(c[4*p], c[4*p+1], c[4*p+2], c[4*p+3]);
}

// ---- k_H: q-recon + splat + horizontal conv (block = rowquad x pack) ----
// MODE 0: q0 from mask; grid-y doubled, y>=NP -> ones pipeline (for ksum).
// MODE 1: recon q from partV; reduce partVk -> persist ksum.
// MODE 2: recon q; read persisted ksum.
template<int MODE>
__global__ __launch_bounds__(384) void k_H(const int* __restrict__ mask,
        const float4* __restrict__ B4,
        const float* __restrict__ partV, const float* __restrict__ partVk,
        float* __restrict__ ksum, const float* __restrict__ qprev, float* __restrict__ qcur,
        float4* __restrict__ H4T, float* __restrict__ H3T,
        float4* __restrict__ H4Tk, float* __restrict__ H3Tk)
{
    __shared__ float4 P4[4][W];       // splat rows (pack<18)
    __shared__ float  qp[4][W];       // q rows (g3 pack)
    __shared__ float  tw50[193], tw3[193];
    const int  t    = threadIdx.x;
    const int  B    = blockIdx.x;
    const int  g0   = blockIdx.y;
    const bool ones = (MODE==0) && (g0 >= NP);
    const int  pack = ones ? g0 - NP : g0;
    const int  r    = t / W, xx = t - (t/W)*W;

    if (t < 193){
        float d = (float)(t - 96);
        tw50[t] = __expf(-d*d*(1.f/5000.f));   // bilateral spatial, sxy=50
        tw3[t]  = __expf(-d*d*(1.f/18.f));     // gaussian spatial,  sxy=3
    }
    float A[4];
    if (pack < NPKB){
        #pragma unroll
        for (int j = 0; j < 4; ++j){
            int c = 4*pack + j;
            if (c == 0)       A[j] = 0.6923648f;                  // 10*sqrt(400*pi)/512
            else if (c <= 70){
                int m = (c <= NM) ? c : c - NM;
                A[j] = 1.3847296f * __expf(-0.0150598f*(float)(m*m));
            } else            A[j] = 0.f;
        }
    }

    // ---- recon q (1 px/thread) + splat ----
    {
        int px = B*384 + t;
        float q;
        if (ones){
            q = 1.f;
        } else if (MODE == 0){
            q = (mask[px]==0) ? 1.f/(1.f+__expf( LCLIP)) : 1.f/(1.f+__expf(-LCLIP));
        } else {
            float m = 0.f;
            #pragma unroll
            for (int p = 0; p < NP; ++p) m += partV[(size_t)p*NPIX + px];
            float kk;
            if (MODE == 1){
                kk = 0.f;
                #pragma unroll
                for (int p = 0; p < NP; ++p) kk += partVk[(size_t)p*NPIX + px];
                kk -= 13.f;                          // remove diagonal from colsum
                if (g0 == 0) ksum[px] = kk;          // persist (iteration-invariant)
            } else {
                kk = ksum[px];
            }
            float duv = (mask[px]==0) ? LCLIP : -LCLIP;
            float delta = duv + kk - 2.f*(m - 13.f*qprev[px]);   // diag removal
            q = 1.f/(1.f+__expf(delta));
        }
        if (!ones && g0 == 0) qcur[px] = q;          // designated writer
        if (pack < NPKB){
            float4 b = B4[(size_t)pack*NPIX + px];
            P4[r][xx] = make_float4(q*A[0]*b.x, q*A[1]*b.y, q*A[2]*b.z, q*A[3]*b.w);
        } else {
            qp[r][xx] = q;
        }
    }
    __syncthreads();

    // ---- H-conv: thread owns output (r, x); P reads broadcast, taps stride-1 ----
    const int x = xx, y = 4*B + r;
    if (pack < NPKB){
        float4 a = make_float4(0.f,0.f,0.f,0.f);
        #pragma unroll 4
        for (int xp = 0; xp < W; ++xp){
            float  w = tw50[x - xp + 96];
            float4 v = P4[r][xp];                    // wave-uniform broadcast
            a.x = fmaf(w,v.x,a.x); a.y = fmaf(w,v.y,a.y);
            a.z = fmaf(w,v.z,a.z); a.w = fmaf(w,v.w,a.w);
        }
        (ones ? H4Tk : H4T)[(size_t)pack*NPIX + x*W + y] = a;    // transposed store
    } else {
        float h = 0.f;
        #pragma unroll 4
        for (int xp = 0; xp < W; ++xp)
            h = fmaf(tw3[x - xp + 96], qp[r][xp], h);
        (ones ? H3Tk : H3T)[x*W + y] = h;
    }
}

// ---- k_V: vertical conv + slice -> scalar partials (block = colquad x pack) ----
__global__ __launch_bounds__(384) void k_V(const float4* __restrict__ B4,
        const float4* __restrict__ H4T, const float4* __restrict__ H4Tk,
        const float* __restrict__ H3T, const float* __restrict__ H3Tk,
        float* __restrict__ partV, float* __restrict__ partVk)
{
    __shared__ float4 Hl[4][W];
    __shared__ float  Hl3[4][W];
    __shared__ float  tw50[193], tw3[193];
    const int  t    = threadIdx.x;
    const int  C    = blockIdx.x;
    const int  g0   = blockIdx.y;
    const bool ones = g0 >= NP;
    const int  pack = ones ? g0 - NP : g0;
    const int  r    = t / W, yy = t - (t/W)*W;

    if (t < 193){
        float d = (float)(t - 96);
        tw50[t] = __expf(-d*d*(1.f/5000.f));
        tw3[t]  = __expf(-d*d*(1.f/18.f));
    }
    // stage this block's 4 H-columns (coalesced: contiguous in y)
    if (pack < NPKB) Hl[r][yy]  = (ones ? H4Tk : H4T)[(size_t)pack*NPIX + (4*C+r)*W + yy];
    else             Hl3[r][yy] = (ones ? H3Tk : H3T)[(4*C+r)*W + yy];
    __syncthreads();

    const int yo = yy, x = 4*C + r, px = yo*W + x;
    float val;
    if (pack < NPKB){
        float4 a = make_float4(0.f,0.f,0.f,0.f);
        #pragma unroll 4
        for (int yp = 0; yp < W; ++yp){
            float  w = tw50[yo - yp + 96];
            float4 v = Hl[r][yp];                    // wave-uniform broadcast
            a.x = fmaf(w,v.x,a.x); a.y = fmaf(w,v.y,a.y);
            a.z = fmaf(w,v.z,a.z); a.w = fmaf(w,v.w,a.w);
        }
        float4 b = B4[(size_t)pack*NPIX + px];       // slice basis at output pixel
        val = a.x*b.x + a.y*b.y + a.z*b.z + a.w*b.w;
    } else {
        float ag = 0.f;
        #pragma unroll 4
        for (int yp = 0; yp < W; ++yp)
            ag = fmaf(tw3[yo - yp + 96], Hl3[r][yp], ag);
        val = 3.f * ag;                              // gaussian compat
    }
    (ones ? partVk : partV)[(size_t)pack*NPIX + px] = val;
}

// ---- final: 5th update + argmax ----
__global__ __launch_bounds__(256) void k_F(const int* __restrict__ mask,
        const float* __restrict__ partV, const float* __restrict__ ksum,
        const float* __restrict__ qprev, float* __restrict__ out){
    int px = blockIdx.x*256 + threadIdx.x;
    float m = 0.f;
    #pragma unroll
    for (int p = 0; p < NP; ++p) m += partV[(size_t)p*NPIX + px];
    float duv = (mask[px]==0) ? LCLIP : -LCLIP;
    float delta = duv + ksum[px] - 2.f*(m - 13.f*qprev[px]);
    out[px] = (delta > 0.f) ? 1.f : 0.f;             // argmax; tie -> label 0
}

extern "C" void kernel_launch(void* const* d_in, const int* in_sizes, int n_in,
                              void* d_out, int out_size, void* d_ws, size_t ws_size,
                              hipStream_t stream){
    const float* img  = (const float*)d_in[0];
    const int*   mask = (const int*)d_in[1];
    float* out = (float*)d_out;
    float* ws  = (float*)d_ws;

    constexpr size_t TBL = (size_t)NPKB*NPIX*4;      // floats in a pack table
    float4* B4    = (float4*)ws;
    float4* H4T   = (float4*)(ws + TBL);
    float4* H4Tk  = (float4*)(ws + 2*TBL);
    float*  base  = ws + 3*TBL;
    float* H3T   = base;
    float* H3Tk  = H3T  + NPIX;
    float* partV = H3Tk + NPIX;                      // [19][NPIX]
    float* partVk= partV + (size_t)NP*NPIX;
    float* qA    = partVk + (size_t)NP*NPIX;
    float* qB    = qA + NPIX;
    float* ksum  = qB + NPIX;

    dim3 b(384);
    k_init<<<dim3(36), dim3(256), 0, stream>>>(img, B4);
    // iter 0: q0 (+ ones pipeline for ksum)
    k_H<0><<<dim3(24,2*NP), b, 0, stream>>>(mask, B4, partV, partVk, ksum, qA, qA, H4T, H3T, H4Tk, H3Tk);
    k_V   <<<dim3(24,2*NP), b, 0, stream>>>(B4, H4T, H4Tk, H3T, H3Tk, partV, partVk);
    // iter 1: recon q1, persist ksum
    k_H<1><<<dim3(24,NP), b, 0, stream>>>(mask, B4, partV, partVk, ksum, qA, qB, H4T, H3T, H4Tk, H3Tk);
    k_V   <<<dim3(24,NP), b, 0, stream>>>(B4, H4T, H4Tk, H3T, H3Tk, partV, partVk);
    // iters 2..4
    k_H<2><<<dim3(24,NP), b, 0, stream>>>(mask, B4, partV, partVk, ksum, qB, qA, H4T, H3T, H4Tk, H3Tk);
    k_V   <<<dim3(24,NP), b, 0, stream>>>(B4, H4T, H4Tk, H3T, H3Tk, partV, partVk);
    k_H<2><<<dim3(24,NP), b, 0, stream>>>(mask, B4, partV, partVk, ksum, qA, qB, H4T, H3T, H4Tk, H3Tk);
    k_V   <<<dim3(24,NP), b, 0, stream>>>(B4, H4T, H4Tk, H3T, H3Tk, partV, partVk);
    k_H<2><<<dim3(24,NP), b, 0, stream>>>(mask, B4, partV, partVk, ksum, qB, qA, H4T, H3T, H4Tk, H3Tk);
    k_V   <<<dim3(24,NP), b, 0, stream>>>(B4, H4T, H4Tk, H3T, H3Tk, partV, partVk);
    // iter 5: final update + argmax (qprev = q4 = qA)
    k_F<<<dim3(36), dim3(256), 0, stream>>>(mask, partV, ksum, qA, out);
}

// Round 14
// 80.675 us; speedup vs baseline: 3.6689x; 1.1022x over previous
//
#include <hip/hip_runtime.h>

constexpr int W    = 96;
constexpr int NPIX = 9216;
constexpr int NM   = 31;     // Fourier modes; tail < 5e-8 per kernel value
constexpr int NPKB = 16;     // 64 channels = DC + 31 cos + 31 sin + pad
constexpr int NP   = 17;     // + sxy=3 gaussian "pack"

constexpr float LCLIP = 18.420681f;   // -log(1e-8)

// ---- init: Fourier basis via 1 sincos + angle-addition recurrence ----
__global__ __launch_bounds__(256) void k_init(const float* __restrict__ img,
                                              float4* __restrict__ B4){
    int px = blockIdx.x*256 + threadIdx.x;
    float th = img[px] * 0.0122718463f;        // 2*pi/512
    float c[64];
    c[0] = 1.f; c[63] = 0.f;
    float s1, c1;
    sincosf(th, &s1, &c1);                     // libm: accurate reduction
    float cm = 1.f, sm = 0.f;
    #pragma unroll
    for (int m = 1; m <= NM; ++m){
        float cn = cm*c1 - sm*s1;              // angle addition: err ~ sqrt(m)*eps
        float sn = sm*c1 + cm*s1;
        cm = cn; sm = sn;
        c[m]    = cm;                          // cos channels 1..31
        c[NM+m] = sm;                          // sin channels 32..62
    }
    #pragma unroll
    for (int p = 0; p < NPKB; ++p)
        B4[(size_t)p*NPIX + px] = make_float4(c[4*p], c[4*p+1], c[4*p+2], c[4*p+3]);
}

// ---- k_H: q-recon + splat + horizontal conv. block = 8 rows x pack, 2 outputs/thread ----
// MODE 0: q0 from mask; grid-y doubled, g0>=NP -> ones pipeline (for ksum).
// MODE 1: recon q from partV; reduce partVk -> persist ksum. MODE 2: recon q; read ksum.
template<int MODE>
__global__ __launch_bounds__(384) void k_H(const int* __restrict__ mask,
        const float4* __restrict__ B4,
        const float* __restrict__ partV, const float* __restrict__ partVk,
        float* __restrict__ ksum, const float* __restrict__ qprev, float* __restrict__ qcur,
        float4* __restrict__ H4T, float* __restrict__ H3T,
        float4* __restrict__ H4Tk, float* __restrict__ H3Tk)
{
    __shared__ float4 P4[8*97];        // padded rows: banks spread per-row
    __shared__ float  qp[8*97];        // g3 pack only
    __shared__ float  tw[193];
    const int  t    = threadIdx.x;
    const int  B    = blockIdx.x;
    const int  g0   = blockIdx.y;
    const bool ones = (MODE==0) && (g0 >= NP);
    const int  pack = ones ? g0 - NP : g0;
    const bool G3   = (pack == NPKB);

    if (t < 193){
        float d = (float)(t - 96);
        tw[t] = G3 ? __expf(-d*d*(1.f/18.f)) : __expf(-d*d*(1.f/5000.f));
    }
    float A[4];
    if (!G3){
        #pragma unroll
        for (int jj = 0; jj < 4; ++jj){
            int cch = 4*pack + jj;
            if (cch == 0)       A[jj] = 0.6923648f;               // 10*sqrt(400*pi)/512
            else if (cch <= 62){
                int m = (cch <= NM) ? cch : cch - NM;
                A[jj] = 1.3847296f * __expf(-0.0150598f*(float)(m*m));
            } else              A[jj] = 0.f;
        }
    }

    // ---- recon q + splat (2 px/thread, coalesced) ----
    #pragma unroll
    for (int k = 0; k < 2; ++k){
        int l  = t + k*384;
        int px = B*768 + l;
        float q;
        if (ones){
            q = 1.f;
        } else if (MODE == 0){
            q = (mask[px]==0) ? 1.f/(1.f+__expf( LCLIP)) : 1.f/(1.f+__expf(-LCLIP));
        } else {
            float m = 0.f;
            #pragma unroll
            for (int p = 0; p < NP; ++p) m += partV[(size_t)p*NPIX + px];
            float kk;
            if (MODE == 1){
                kk = 0.f;
                #pragma unroll
                for (int p = 0; p < NP; ++p) kk += partVk[(size_t)p*NPIX + px];
                kk -= 13.f;                          // remove diagonal from colsum
                if (g0 == 0) ksum[px] = kk;          // persist (iteration-invariant)
            } else {
                kk = ksum[px];
            }
            float duv = (mask[px]==0) ? LCLIP : -LCLIP;
            float delta = duv + kk - 2.f*(m - 13.f*qprev[px]);   // diag removal
            q = 1.f/(1.f+__expf(delta));
        }
        if (!ones && g0 == 0) qcur[px] = q;          // designated writer
        int ryl = l/96, xx = l - ryl*96;
        if (!G3){
            float4 b = B4[(size_t)pack*NPIX + px];
            P4[ryl*97 + xx] = make_float4(q*A[0]*b.x, q*A[1]*b.y, q*A[2]*b.z, q*A[3]*b.w);
        } else {
            qp[ryl*97 + xx] = q;
        }
    }
    __syncthreads();

    // ---- H-conv: thread (r = t&7, xg = t>>3) owns outputs x = xg, xg+48 of row y ----
    const int r = t & 7, xg = t >> 3;
    const int y = 8*B + r;
    if (!G3){
        float4 a0 = make_float4(0.f,0.f,0.f,0.f), a1 = a0;
        #pragma unroll 4
        for (int xp = 0; xp < W; ++xp){
            float4 v  = P4[r*97 + xp];               // 8 bank-spread broadcasts
            float  w0 = tw[xg - xp + 96];            // ds_read2_b32 pair
            float  w1 = tw[xg - xp + 96 + 48];
            a0.x = fmaf(w0,v.x,a0.x); a0.y = fmaf(w0,v.y,a0.y);
            a0.z = fmaf(w0,v.z,a0.z); a0.w = fmaf(w0,v.w,a0.w);
            a1.x = fmaf(w1,v.x,a1.x); a1.y = fmaf(w1,v.y,a1.y);
            a1.z = fmaf(w1,v.z,a1.z); a1.w = fmaf(w1,v.w,a1.w);
        }
        float4* dst = ones ? H4Tk : H4T;
        dst[(size_t)pack*NPIX + xg*W      + y] = a0; // transposed store, 8-lane chunks
        dst[(size_t)pack*NPIX + (xg+48)*W + y] = a1;
    } else {
        float h0 = 0.f, h1 = 0.f;
        #pragma unroll 4
        for (int xp = 0; xp < W; ++xp){
            float qv = qp[r*97 + xp];
            h0 = fmaf(tw[xg - xp + 96],      qv, h0);
            h1 = fmaf(tw[xg - xp + 96 + 48], qv, h1);
        }
        float* dg = ones ? H3Tk : H3T;
        dg[xg*W + y] = h0; dg[(xg+48)*W + y] = h1;
    }
}

// ---- k_V: vertical conv + slice. block = 8 cols x pack, 2 outputs/thread ----
__global__ __launch_bounds__(384) void k_V(const float4* __restrict__ B4,
        const float4* __restrict__ H4T, const float4* __restrict__ H4Tk,
        const float* __restrict__ H3T, const float* __restrict__ H3Tk,
        float* __restrict__ partV, float* __restrict__ partVk)
{
    __shared__ float4 Hl[8*97];
    __shared__ float  Hl3[8*97];
    __shared__ float  tw[193];
    const int  t    = threadIdx.x;
    const int  C    = blockIdx.x;
    const int  g0   = blockIdx.y;
    const bool ones = g0 >= NP;
    const int  pack = ones ? g0 - NP : g0;
    const bool G3   = (pack == NPKB);

    if (t < 193){
        float d = (float)(t - 96);
        tw[t] = G3 ? __expf(-d*d*(1.f/18.f)) : __expf(-d*d*(1.f/5000.f));
    }
    // stage 8 H-columns (coalesced: yy fastest)
    #pragma unroll
    for (int k = 0; k < 2; ++k){
        int l = t + k*384;
        int col = l/96, yy = l - col*96;
        if (!G3) Hl[col*97 + yy]  = (ones ? H4Tk : H4T)[(size_t)pack*NPIX + (8*C+col)*W + yy];
        else     Hl3[col*97 + yy] = (ones ? H3Tk : H3T)[(8*C+col)*W + yy];
    }
    __syncthreads();

    const int r = t & 7, yg = t >> 3;            // col r, outputs yo = yg, yg+48
    const int x = 8*C + r;
    if (!G3){
        float4 a0 = make_float4(0.f,0.f,0.f,0.f), a1 = a0;
        #pragma unroll 4
        for (int yp = 0; yp < W; ++yp){
            float4 v  = Hl[r*97 + yp];
            float  w0 = tw[yg - yp + 96];
            float  w1 = tw[yg - yp + 96 + 48];
            a0.x = fmaf(w0,v.x,a0.x); a0.y = fmaf(w0,v.y,a0.y);
            a0.z = fmaf(w0,v.z,a0.z); a0.w = fmaf(w0,v.w,a0.w);
            a1.x = fmaf(w1,v.x,a1.x); a1.y = fmaf(w1,v.y,a1.y);
            a1.z = fmaf(w1,v.z,a1.z); a1.w = fmaf(w1,v.w,a1.w);
        }
        int px0 = yg*W + x, px1 = (yg+48)*W + x;
        float4 b0 = B4[(size_t)pack*NPIX + px0];     // slice basis at output pixel
        float4 b1 = B4[(size_t)pack*NPIX + px1];
        float* dst = ones ? partVk : partV;
        dst[(size_t)pack*NPIX + px0] = a0.x*b0.x + a0.y*b0.y + a0.z*b0.z + a0.w*b0.w;
        dst[(size_t)pack*NPIX + px1] = a1.x*b1.x + a1.y*b1.y + a1.z*b1.z + a1.w*b1.w;
    } else {
        float h0 = 0.f, h1 = 0.f;
        #pragma unroll 4
        for (int yp = 0; yp < W; ++yp){
            float v = Hl3[r*97 + yp];
            h0 = fmaf(tw[yg - yp + 96],      v, h0);
            h1 = fmaf(tw[yg - yp + 96 + 48], v, h1);
        }
        float* dst = ones ? partVk : partV;
        dst[(size_t)pack*NPIX + yg*W + x]      = 3.f*h0;   // gaussian compat
        dst[(size_t)pack*NPIX + (yg+48)*W + x] = 3.f*h1;
    }
}

// ---- final: 5th update + argmax ----
__global__ __launch_bounds__(256) void k_F(const int* __restrict__ mask,
        const float* __restrict__ partV, const float* __restrict__ ksum,
        const float* __restrict__ qprev, float* __restrict__ out){
    int px = blockIdx.x*256 + threadIdx.x;
    float m = 0.f;
    #pragma unroll
    for (int p = 0; p < NP; ++p) m += partV[(size_t)p*NPIX + px];
    float duv = (mask[px]==0) ? LCLIP : -LCLIP;
    float delta = duv + ksum[px] - 2.f*(m - 13.f*qprev[px]);
    out[px] = (delta > 0.f) ? 1.f : 0.f;             // argmax; tie -> label 0
}

extern "C" void kernel_launch(void* const* d_in, const int* in_sizes, int n_in,
                              void* d_out, int out_size, void* d_ws, size_t ws_size,
                              hipStream_t stream){
    const float* img  = (const float*)d_in[0];
    const int*   mask = (const int*)d_in[1];
    float* out = (float*)d_out;
    float* ws  = (float*)d_ws;

    constexpr size_t TBL = (size_t)NPKB*NPIX*4;      // floats in a pack table
    float4* B4    = (float4*)ws;
    float4* H4T   = (float4*)(ws + TBL);
    float4* H4Tk  = (float4*)(ws + 2*TBL);
    float*  base  = ws + 3*TBL;
    float* H3T   = base;
    float* H3Tk  = H3T  + NPIX;
    float* partV = H3Tk + NPIX;                      // [17][NPIX]
    float* partVk= partV + (size_t)NP*NPIX;
    float* qA    = partVk + (size_t)NP*NPIX;
    float* qB    = qA + NPIX;
    float* ksum  = qB + NPIX;

    dim3 b(384);
    k_init<<<dim3(36), dim3(256), 0, stream>>>(img, B4);
    // iter 0: q0 (+ ones pipeline for ksum)
    k_H<0><<<dim3(12,2*NP), b, 0, stream>>>(mask, B4, partV, partVk, ksum, qA, qA, H4T, H3T, H4Tk, H3Tk);
    k_V   <<<dim3(12,2*NP), b, 0, stream>>>(B4, H4T, H4Tk, H3T, H3Tk, partV, partVk);
    // iter 1: recon q1, persist ksum
    k_H<1><<<dim3(12,NP), b, 0, stream>>>(mask, B4, partV, partVk, ksum, qA, qB, H4T, H3T, H4Tk, H3Tk);
    k_V   <<<dim3(12,NP), b, 0, stream>>>(B4, H4T, H4Tk, H3T, H3Tk, partV, partVk);
    // iters 2..4
    k_H<2><<<dim3(12,NP), b, 0, stream>>>(mask, B4, partV, partVk, ksum, qB, qA, H4T, H3T, H4Tk, H3Tk);
    k_V   <<<dim3(12,NP), b, 0, stream>>>(B4, H4T, H4Tk, H3T, H3Tk, partV, partVk);
    k_H<2><<<dim3(12,NP), b, 0, stream>>>(mask, B4, partV, partVk, ksum, qA, qB, H4T, H3T, H4Tk, H3Tk);
    k_V   <<<dim3(12,NP), b, 0, stream>>>(B4, H4T, H4Tk, H3T, H3Tk, partV, partVk);
    k_H<2><<<dim3(12,NP), b, 0, stream>>>(mask, B4, partV, partVk, ksum, qB, qA, H4T, H3T, H4Tk, H3Tk);
    k_V   <<<dim3(12,NP), b, 0, stream>>>(B4, H4T, H4Tk, H3T, H3Tk, partV, partVk);
    // iter 5: final update + argmax (qprev = q4 = qA)
    k_F<<<dim3(36), dim3(256), 0, stream>>>(mask, partV, ksum, qA, out);
}